// Round 14
// baseline (158.662 us; speedup 1.0000x reference)
//
#include <hip/hip_runtime.h>
#include <cstdint>

// Chamfer distance, B=8, N=M=4096, D=128, f32 in, scalar f32 out.
// R14: barrier-free wave-autonomous GEMM. R8-R12 plateau at ~47us with all
// pipes <35% busy: the per-tile __syncthreads phase-locks waves (LDS burst /
// MFMA burst / vmcnt drain serialize). Now each wave owns 64 rows x 512 cols
// and DMA-stages its OWN private 4KB B-slab (16 cols, dbuf) -- it reads only
// what it wrote, so ordering needs only its own vmcnt (explicit
// s_waitcnt vmcnt(0); ~300cyc L2 stall staggered across waves). ZERO hot-loop
// barriers. 4 ds_read_b128 + 16 MFMA per slab. LDS 32KB/block; 4096 waves.
// Workspace: xb(8M) yb(8M) x2(128K) y2(128K) rowpart(1M) colpart(8M).

#define B_   8
#define N_   4096
#define M_   4096
#define D_   128
#define WCOLS 512                  // cols per wave
#define SLABS (WCOLS / 16)         // 32 slabs of 16 cols
#define RG_  (N_ / 64)             // 64 row-groups per batch
#define CG_  (M_ / WCOLS)          // 8 col-groups per batch

typedef __bf16 bf16x8 __attribute__((ext_vector_type(8)));
typedef float  f32x4  __attribute__((ext_vector_type(4)));
typedef unsigned int u32;

static __device__ __forceinline__ unsigned short f2bf(float f) {
  unsigned u = __float_as_uint(f);
  u += 0x7FFFu + ((u >> 16) & 1u);   // round-to-nearest-even
  return (unsigned short)(u >> 16);
}

static __device__ __forceinline__ void gld16(void* lds, const void* g) {
  __builtin_amdgcn_global_load_lds(
      (const __attribute__((address_space(1))) void*)g,
      (__attribute__((address_space(3))) void*)lds, 16, 0, 0);
}

// Pass 1: wave handles 2 rows (32 lanes x float4 each). xb = bf16(-2x),
// yb = bf16(y), fp32 norms. Also zeroes the output scalar (block 0).
__global__ __launch_bounds__(256) void pass1_prep(
    const float* __restrict__ x, const float* __restrict__ y,
    unsigned short* __restrict__ xb, unsigned short* __restrict__ yb,
    float* __restrict__ x2, float* __restrict__ y2,
    float* __restrict__ out)
{
  if (blockIdx.x == 0 && threadIdx.x == 0) out[0] = 0.0f;
  const int ROWS = B_ * N_;
  int gw   = (blockIdx.x * 256 + threadIdx.x) >> 6;   // wave id
  int lane = threadIdx.x & 63;
  int half = lane >> 5, sub = lane & 31;
  int row2 = gw * 2 + half;                  // 0 .. 2*ROWS-1 (x rows then y rows)
  bool isx = row2 < ROWS;
  const float* src; unsigned short* dst; float* nrm; int row;
  if (isx) { src = x; dst = xb; nrm = x2; row = row2; }
  else     { src = y; dst = yb; nrm = y2; row = row2 - ROWS; }
  size_t base = (size_t)row * D_ + sub * 4;
  float4 v = *(const float4*)(src + base);
  float sx = isx ? -2.0f : 1.0f;
  u32 p0 = (u32)f2bf(sx * v.x) | ((u32)f2bf(sx * v.y) << 16);
  u32 p1 = (u32)f2bf(sx * v.z) | ((u32)f2bf(sx * v.w) << 16);
  *(uint2*)(dst + base) = make_uint2(p0, p1);
  float s = v.x * v.x + v.y * v.y + v.z * v.z + v.w * v.w;
  #pragma unroll
  for (int m = 1; m < 32; m <<= 1) s += __shfl_xor(s, m, 64);
  if (sub == 0) nrm[row] = s;
}

// Pass 2: 4 independent waves per block. Wave = 64 x-rows (rt=4) x 512 y-cols
// (32 slabs of 16). Private dbuf LDS slab (2 x 4KB), XOR-16 swizzle
// (row r of slab, logical 16B-chunk c at physical chunk c^r; 256 B rows).
// Fragment layouts (HW-verified):
//   A/B operand: lane holds elems [row=lane&15][k=(lane>>4)*8 + 0..7]
//   C/D:         lane reg r holds [row=(lane>>4)*4+r][col=lane&15]
// acc init = x2_i, so final a = x2_i - 2<x,y>; s = a + y2_j = d^2.
// NO __syncthreads anywhere. Per-slab ordering: own-wave s_waitcnt vmcnt(0).
__global__ __launch_bounds__(256) void pass2_tile(
    const unsigned short* __restrict__ xb, const unsigned short* __restrict__ yb,
    const float* __restrict__ x2, const float* __restrict__ y2,
    float* __restrict__ rowpart, float* __restrict__ colpart)
{
  __shared__ unsigned short ys[4 * 4096];    // 4 waves x (2 x 4KB) private dbuf

  const int tid  = threadIdx.x;
  const int wave = tid >> 6;                 // 0..3
  const int lane = tid & 63;
  const int quad = lane >> 4;
  const int l15  = lane & 15;

  const int id = blockIdx.x;           // 0..1023
  const int b  = id & 7;
  const int j  = id >> 3;              // 0..127
  const int cg = j >> 4;               // 0..7  col group (512 cols)
  const int rg = (j & 15) * 4 + wave;  // 0..63 row group (64 rows)
  const int n0 = rg * 64;
  const int m0 = cg * WCOLS;

  char* wbuf = (char*)ys + wave * 8192;   // this wave's 8KB (two 4KB buffers)

  // DMA lane offsets within a 4KB slab (16 rows x 256B):
  // instr i covers bytes i*1024 + lane*16: row r=i*4+(lane>>4), physical
  // chunk lane&15, logical chunk c=(lane&15)^r -> src elem r*D + c*8.
  int srcoff[4];
  #pragma unroll
  for (int i = 0; i < 4; ++i) {
    int r = i * 4 + (lane >> 4);
    int c = (lane & 15) ^ r;
    srcoff[i] = r * D_ + c * 8;
  }

  // A fragments: direct global->register (16 x 16B from L2), rows n0+rt*16+l15.
  bf16x8 afrag[4][4];   // [kb][rt]
  const size_t xrow0 = (size_t)b * N_ + n0;
  #pragma unroll
  for (int kb = 0; kb < 4; ++kb)
    #pragma unroll
    for (int rt = 0; rt < 4; ++rt)
      afrag[kb][rt] = *(const bf16x8*)(xb + (xrow0 + rt * 16 + l15) * D_ + kb * 32 + quad * 8);

  // x2 for this wave's 16 output rows (slab-invariant), f32x4 for acc init
  f32x4 xvv[4];
  #pragma unroll
  for (int rt = 0; rt < 4; ++rt)
    #pragma unroll
    for (int r = 0; r < 4; ++r)
      xvv[rt][r] = x2[(size_t)b * N_ + n0 + rt * 16 + quad * 4 + r];

  const float FINF = __uint_as_float(0x7F800000u);
  float rmin2[4][4];
  #pragma unroll
  for (int rt = 0; rt < 4; ++rt)
    #pragma unroll
    for (int r = 0; r < 4; ++r) rmin2[rt][r] = FINF;

  const unsigned short* ybase = yb + ((size_t)b * M_ + m0) * D_;
  const float*          y2ch  = y2 + (size_t)b * M_ + m0;
  float* cpart = colpart + (size_t)rg * (B_ * M_) + (size_t)b * M_ + m0;

  // preload slab 0 into buffer 0
  #pragma unroll
  for (int i = 0; i < 4; ++i) gld16(wbuf + i * 1024, ybase + srcoff[i]);

  #pragma unroll 1
  for (int t = 0; t < SLABS; ++t) {
    const int buf = (t & 1) * 4096;
    float yv = y2ch[t * 16 + l15];     // y^2 for this lane's col

    if (t + 1 < SLABS) {               // prefetch next slab into other buffer
      const unsigned short* src = ybase + (t + 1) * 16 * D_;
      char* dst = wbuf + (4096 - buf);
      #pragma unroll
      for (int i = 0; i < 4; ++i) gld16(dst + i * 1024, src + srcoff[i]);
    }

    // own-wave DMA drain (L2-latency stall, staggered across waves; no barrier)
    asm volatile("s_waitcnt vmcnt(0)" ::: "memory");

    bf16x8 bfr[4];
    #pragma unroll
    for (int kb = 0; kb < 4; ++kb)
      bfr[kb] = *(const bf16x8*)(wbuf + buf + l15 * 256 + (((kb * 4 + quad) ^ l15) * 16));

    f32x4 a[4];
    #pragma unroll
    for (int rt = 0; rt < 4; ++rt) a[rt] = xvv[rt];   // acc init = x2
    #pragma unroll
    for (int kb = 0; kb < 4; ++kb)
      #pragma unroll
      for (int rt = 0; rt < 4; ++rt)
        a[rt] = __builtin_amdgcn_mfma_f32_16x16x32_bf16(afrag[kb][rt], bfr[kb], a[rt], 0, 0, 0);

    float cm = FINF;
    #pragma unroll
    for (int rt = 0; rt < 4; ++rt) {
      #pragma unroll
      for (int r = 0; r < 4; ++r) {
        float s = a[rt][r] + yv;               // = x2_i + y2_j - 2<x,y>
        rmin2[rt][r] = fminf(rmin2[rt][r], s);
        cm = fminf(cm, s);
      }
    }
    // col-min over the wave's 64 rows: reduce across quads, store 16 floats
    cm = fminf(cm, __shfl_xor(cm, 16, 64));
    cm = fminf(cm, __shfl_xor(cm, 32, 64));
    if (lane < 16) cpart[t * 16 + lane] = cm;
  }

  // Row mins over this wave's 512 cols: reduce across 16 col-lanes, store.
  #pragma unroll
  for (int rt = 0; rt < 4; ++rt) {
    #pragma unroll
    for (int r = 0; r < 4; ++r) {
      float v = rmin2[rt][r];
      v = fminf(v, __shfl_xor(v, 1, 64));
      v = fminf(v, __shfl_xor(v, 2, 64));
      v = fminf(v, __shfl_xor(v, 4, 64));
      v = fminf(v, __shfl_xor(v, 8, 64));
      if (l15 == 0)
        rowpart[(size_t)cg * (B_ * N_) + (size_t)b * N_ + n0 + rt * 16 + quad * 4 + r] = v;
    }
  }
}

// Pass 3: reduce partials (min over 8 col-groups for rows, 64 row-groups for
// cols), sqrt, sum, atomicAdd into the pre-zeroed output scalar.
__global__ __launch_bounds__(256) void pass3_final(
    const float* __restrict__ rowpart, const float* __restrict__ colpart,
    float* __restrict__ out)
{
  const int BN = B_ * N_;
  float s1 = 0.0f, s2 = 0.0f;
  for (int i = blockIdx.x * 256 + threadIdx.x; i < BN; i += 64 * 256) {
    float r = rowpart[i];
    #pragma unroll
    for (int c = 1; c < CG_; ++c) r = fminf(r, rowpart[c * BN + i]);
    s1 += sqrtf(fmaxf(r, 0.0f));
    float m = colpart[i];
    #pragma unroll
    for (int g = 1; g < RG_; ++g) m = fminf(m, colpart[g * BN + i]);
    s2 += sqrtf(fmaxf(m, 0.0f));
  }
  float s = s1 + s2;
  #pragma unroll
  for (int m = 1; m < 64; m <<= 1) s += __shfl_xor(s, m, 64);
  __shared__ float r1[4];
  int wave = threadIdx.x >> 6, lane = threadIdx.x & 63;
  if (lane == 0) r1[wave] = s;
  __syncthreads();
  if (threadIdx.x == 0)
    atomicAdd(out, (r1[0] + r1[1] + r1[2] + r1[3]) / (float)(B_ * N_));
}

extern "C" void kernel_launch(void* const* d_in, const int* in_sizes, int n_in,
                              void* d_out, int out_size, void* d_ws, size_t ws_size,
                              hipStream_t stream)
{
  const float* x = (const float*)d_in[0];
  const float* y = (const float*)d_in[1];
  char* ws = (char*)d_ws;

  unsigned short* xb = (unsigned short*)(ws);
  unsigned short* yb = (unsigned short*)(ws + (8u << 20));
  float* x2      = (float*)(ws + (16u << 20));
  float* y2      = (float*)(ws + (16u << 20) + (1u << 17));
  float* rowpart = (float*)(ws + (16u << 20) + (2u << 17));               // 8*B*N*4  = 1 MB
  float* colpart = (float*)(ws + (16u << 20) + (2u << 17) + (1u << 20));  // 64*B*M*4 = 8 MB
  float* outf = (float*)d_out;

  pass1_prep<<<(B_ * N_) / 4, 256, 0, stream>>>(x, y, xb, yb, x2, y2, outf);

  pass2_tile<<<B_ * RG_ * CG_ / 4, 256, 0, stream>>>(xb, yb, x2, y2, rowpart, colpart);

  pass3_final<<<64, 256, 0, stream>>>(rowpart, colpart, outf);
}